// Round 1
// baseline (261.014 us; speedup 1.0000x reference)
//
#include <hip/hip_runtime.h>
#include <hip/hip_bf16.h>
#include <math.h>

#define SCAN_THREADS 1024
#define MAX_G 10240

// ---------------- scan: exclusive prefix sum of graph sizes ----------------
__global__ __launch_bounds__(SCAN_THREADS) void scan_kernel(
    const int* __restrict__ gsize, int* __restrict__ offs, int G)
{
    __shared__ int gs[MAX_G];
    __shared__ int part[SCAN_THREADS];
    int t = threadIdx.x;
    int chunk = (G + SCAN_THREADS - 1) / SCAN_THREADS;
    int total = chunk * SCAN_THREADS;
    for (int i = t; i < total && i < MAX_G; i += SCAN_THREADS)
        gs[i] = (i < G) ? gsize[i] : 0;
    __syncthreads();
    int base = t * chunk;
    int s = 0;
    for (int u = 0; u < chunk; ++u) s += gs[base + u];
    part[t] = s;
    __syncthreads();
    // Hillis-Steele inclusive scan over partials
    for (int d = 1; d < SCAN_THREADS; d <<= 1) {
        int v = (t >= d) ? part[t - d] : 0;
        __syncthreads();
        part[t] += v;
        __syncthreads();
    }
    int run = (t == 0) ? 0 : part[t - 1];
    for (int u = 0; u < chunk; ++u) {
        int i = base + u;
        if (i < G) { offs[i] = run; run += gs[i]; }
    }
}

// ---------------- pooling: mean + max per graph, one wave per graph --------
__global__ __launch_bounds__(256) void pool_kernel(
    const float* __restrict__ feats, const int* __restrict__ offs,
    const int* __restrict__ gsize, float* __restrict__ pooled, int G)
{
    int wave = threadIdx.x >> 6;
    int lane = threadIdx.x & 63;
    int g = blockIdx.x * 4 + wave;
    if (g >= G) return;
    int start = offs[g];
    int n = gsize[g];
    const float4* p = (const float4*)feats + (size_t)start * 32;  // 32 float4 per row (D=128)

    float sx = 0.f, sy = 0.f, sz = 0.f, sw = 0.f;
    const float NEG = -3.402823466e38f;
    float mx = NEG, my = NEG, mz = NEG, mw = NEG;

    int npairs = n >> 1;
    int i = 0;
    for (; i + 4 <= npairs; i += 4) {
        float4 v0 = p[(size_t)(i + 0) * 64 + lane];
        float4 v1 = p[(size_t)(i + 1) * 64 + lane];
        float4 v2 = p[(size_t)(i + 2) * 64 + lane];
        float4 v3 = p[(size_t)(i + 3) * 64 + lane];
        sx += v0.x + v1.x + v2.x + v3.x;
        sy += v0.y + v1.y + v2.y + v3.y;
        sz += v0.z + v1.z + v2.z + v3.z;
        sw += v0.w + v1.w + v2.w + v3.w;
        mx = fmaxf(fmaxf(fmaxf(mx, v0.x), fmaxf(v1.x, v2.x)), v3.x);
        my = fmaxf(fmaxf(fmaxf(my, v0.y), fmaxf(v1.y, v2.y)), v3.y);
        mz = fmaxf(fmaxf(fmaxf(mz, v0.z), fmaxf(v1.z, v2.z)), v3.z);
        mw = fmaxf(fmaxf(fmaxf(mw, v0.w), fmaxf(v1.w, v2.w)), v3.w);
    }
    for (; i < npairs; ++i) {
        float4 v = p[(size_t)i * 64 + lane];
        sx += v.x; sy += v.y; sz += v.z; sw += v.w;
        mx = fmaxf(mx, v.x); my = fmaxf(my, v.y);
        mz = fmaxf(mz, v.z); mw = fmaxf(mw, v.w);
    }
    if ((n & 1) && lane < 32) {
        float4 v = p[(size_t)(n - 1) * 32 + lane];
        sx += v.x; sy += v.y; sz += v.z; sw += v.w;
        mx = fmaxf(mx, v.x); my = fmaxf(my, v.y);
        mz = fmaxf(mz, v.z); mw = fmaxf(mw, v.w);
    }
    // combine the two half-wave accumulators (rows of opposite parity)
    sx += __shfl_xor(sx, 32); sy += __shfl_xor(sy, 32);
    sz += __shfl_xor(sz, 32); sw += __shfl_xor(sw, 32);
    mx = fmaxf(mx, __shfl_xor(mx, 32)); my = fmaxf(my, __shfl_xor(my, 32));
    mz = fmaxf(mz, __shfl_xor(mz, 32)); mw = fmaxf(mw, __shfl_xor(mw, 32));

    float4 outv;
    if (lane < 32) {
        float invn = 1.0f / (float)n;
        outv.x = sx * invn; outv.y = sy * invn; outv.z = sz * invn; outv.w = sw * invn;
    } else {
        outv.x = mx; outv.y = my; outv.z = mz; outv.w = mw;
    }
    // lanes 0..31 -> mean cols [0,128), lanes 32..63 -> max cols [128,256)
    ((float4*)pooled)[(size_t)g * 64 + lane] = outv;
}

// ---------------- fused 3-layer MLP: 16 graphs per block -------------------
__global__ __launch_bounds__(256) void mlp_kernel(
    const float* __restrict__ pooled,
    const float* __restrict__ W0, const float* __restrict__ b0,
    const float* __restrict__ W1, const float* __restrict__ b1,
    const float* __restrict__ W2, const float* __restrict__ b2,
    float* __restrict__ out, int G)
{
    __shared__ float X[16 * 256];
    __shared__ float H0[16 * 256];
    __shared__ float H1[16 * 128];
    int t = threadIdx.x;
    int g0 = blockIdx.x * 16;
    int ng = min(16, G - g0);

    // load pooled tile [16][256] (zero-pad tail graphs)
    {
        const float4* src = (const float4*)(pooled + (size_t)g0 * 256);
        float4* dx = (float4*)X;
        int nval4 = ng * 64;
        #pragma unroll
        for (int i = 0; i < 4; ++i) {
            int idx = t + i * 256;
            float4 v;
            if (idx < nval4) v = src[idx];
            else { v.x = v.y = v.z = v.w = 0.f; }
            dx[idx] = v;
        }
    }
    __syncthreads();

    // ---- layer 0: H0[16][256] = relu(X @ W0 + b0), W0 is [256][256] row-major
    {
        int j0 = t & 127;
        int gh = t >> 7;          // 0/1 -> graphs gh*8 .. gh*8+7
        int j1 = j0 + 128;
        float acc0[8], acc1[8];
        float bb0 = b0[j0], bb1 = b0[j1];
        #pragma unroll
        for (int q = 0; q < 8; ++q) { acc0[q] = bb0; acc1[q] = bb1; }
        const float4* X4 = (const float4*)X;
        for (int k4 = 0; k4 < 64; ++k4) {
            const float* Wk = W0 + (size_t)k4 * 4 * 256;
            float wa0 = Wk[j0],       wa1 = Wk[256 + j0];
            float wa2 = Wk[512 + j0], wa3 = Wk[768 + j0];
            float wb0 = Wk[j1],       wb1 = Wk[256 + j1];
            float wb2 = Wk[512 + j1], wb3 = Wk[768 + j1];
            #pragma unroll
            for (int q = 0; q < 8; ++q) {
                float4 x = X4[(gh * 8 + q) * 64 + k4];   // LDS broadcast
                acc0[q] = fmaf(x.x, wa0, acc0[q]);
                acc0[q] = fmaf(x.y, wa1, acc0[q]);
                acc0[q] = fmaf(x.z, wa2, acc0[q]);
                acc0[q] = fmaf(x.w, wa3, acc0[q]);
                acc1[q] = fmaf(x.x, wb0, acc1[q]);
                acc1[q] = fmaf(x.y, wb1, acc1[q]);
                acc1[q] = fmaf(x.z, wb2, acc1[q]);
                acc1[q] = fmaf(x.w, wb3, acc1[q]);
            }
        }
        #pragma unroll
        for (int q = 0; q < 8; ++q) {
            H0[(gh * 8 + q) * 256 + j0] = fmaxf(acc0[q], 0.f);
            H0[(gh * 8 + q) * 256 + j1] = fmaxf(acc1[q], 0.f);
        }
    }
    __syncthreads();

    // ---- layer 1: H1[16][128] = relu(H0 @ W1 + b1), W1 is [256][128]
    {
        int jl = t & 63;
        int gq = t >> 6;          // 0..3 -> graphs gq*4 .. gq*4+3
        float acc0[4], acc1[4];
        float bb0 = b1[jl], bb1 = b1[jl + 64];
        #pragma unroll
        for (int q = 0; q < 4; ++q) { acc0[q] = bb0; acc1[q] = bb1; }
        const float4* H04 = (const float4*)H0;
        for (int k4 = 0; k4 < 64; ++k4) {
            const float* Wk = W1 + (size_t)k4 * 4 * 128;
            float wa0 = Wk[jl],       wa1 = Wk[128 + jl];
            float wa2 = Wk[256 + jl], wa3 = Wk[384 + jl];
            float wb0 = Wk[64 + jl],  wb1 = Wk[192 + jl];
            float wb2 = Wk[320 + jl], wb3 = Wk[448 + jl];
            #pragma unroll
            for (int q = 0; q < 4; ++q) {
                float4 x = H04[(gq * 4 + q) * 64 + k4];  // LDS broadcast
                acc0[q] = fmaf(x.x, wa0, acc0[q]);
                acc0[q] = fmaf(x.y, wa1, acc0[q]);
                acc0[q] = fmaf(x.z, wa2, acc0[q]);
                acc0[q] = fmaf(x.w, wa3, acc0[q]);
                acc1[q] = fmaf(x.x, wb0, acc1[q]);
                acc1[q] = fmaf(x.y, wb1, acc1[q]);
                acc1[q] = fmaf(x.z, wb2, acc1[q]);
                acc1[q] = fmaf(x.w, wb3, acc1[q]);
            }
        }
        #pragma unroll
        for (int q = 0; q < 4; ++q) {
            H1[(gq * 4 + q) * 128 + jl]      = fmaxf(acc0[q], 0.f);
            H1[(gq * 4 + q) * 128 + jl + 64] = fmaxf(acc1[q], 0.f);
        }
    }
    __syncthreads();

    // ---- layer 2: out[g] = sigmoid(H1[g] . W2 + b2)
    {
        int gi = t >> 4;          // 0..15
        int sub = t & 15;
        float acc = 0.f;
        #pragma unroll
        for (int kk = 0; kk < 8; ++kk) {
            int k = sub + kk * 16;
            acc = fmaf(H1[gi * 128 + k], W2[k], acc);
        }
        acc += __shfl_xor(acc, 8);
        acc += __shfl_xor(acc, 4);
        acc += __shfl_xor(acc, 2);
        acc += __shfl_xor(acc, 1);
        if (sub == 0 && gi < ng) {
            float z = acc + b2[0];
            out[g0 + gi] = 1.0f / (1.0f + expf(-z));
        }
    }
}

extern "C" void kernel_launch(void* const* d_in, const int* in_sizes, int n_in,
                              void* d_out, int out_size, void* d_ws, size_t ws_size,
                              hipStream_t stream) {
    const float* feats = (const float*)d_in[0];
    const int*   gsize = (const int*)d_in[1];
    const float* W0 = (const float*)d_in[2];
    const float* b0 = (const float*)d_in[3];
    const float* W1 = (const float*)d_in[4];
    const float* b1 = (const float*)d_in[5];
    const float* W2 = (const float*)d_in[6];
    const float* b2 = (const float*)d_in[7];
    float* out = (float*)d_out;

    int G = in_sizes[1];

    int*   offs   = (int*)d_ws;
    float* pooled = (float*)((char*)d_ws + 65536);

    scan_kernel<<<1, SCAN_THREADS, 0, stream>>>(gsize, offs, G);
    pool_kernel<<<(G + 3) / 4, 256, 0, stream>>>(feats, offs, gsize, pooled, G);
    mlp_kernel<<<(G + 15) / 16, 256, 0, stream>>>(pooled, W0, b0, W1, b1, W2, b2, out, G);
}

// Round 3
// 204.194 us; speedup vs baseline: 1.2783x; 1.2783x over previous
//
#include <hip/hip_runtime.h>
#include <hip/hip_bf16.h>
#include <math.h>

#define GPB 8   // graphs per block

typedef float fx4 __attribute__((ext_vector_type(4)));

__global__ __launch_bounds__(256) void fused_pool_mlp_kernel(
    const float* __restrict__ feats, const int* __restrict__ gsize,
    const float* __restrict__ W0, const float* __restrict__ b0,
    const float* __restrict__ W1, const float* __restrict__ b1,
    const float* __restrict__ W2, const float* __restrict__ b2,
    float* __restrict__ out, int G)
{
    __shared__ __align__(16) float4 X4[GPB * 64];   // pooled [GPB][256]
    __shared__ __align__(16) float  H0[GPB * 256];
    __shared__ __align__(16) float  H1[GPB * 128];
    __shared__ int soff[GPB], ssize[GPB];
    __shared__ int red[4];

    int t    = threadIdx.x;
    int lane = t & 63;
    int wave = t >> 6;
    int g0   = blockIdx.x * GPB;

    // ---- per-block base offset: sum gsize[0:g0) cooperatively (gsize is L2-hot)
    int partial = 0;
    for (int i = t; i < g0; i += 256) partial += gsize[i];
    #pragma unroll
    for (int d = 32; d > 0; d >>= 1) partial += __shfl_xor(partial, d);
    if (lane == 0) red[wave] = partial;
    __syncthreads();
    if (t == 0) {
        int base = red[0] + red[1] + red[2] + red[3];
        #pragma unroll
        for (int q = 0; q < GPB; ++q) {
            int g = g0 + q;
            int n = (g < G) ? gsize[g] : 0;
            soff[q] = base; ssize[q] = n; base += n;
        }
    }
    __syncthreads();

    // ---- pooling: each wave pools 2 graphs (mean lanes 0-31, max lanes 32-63)
    const float NEG = -3.402823466e38f;
    #pragma unroll
    for (int qq = 0; qq < GPB / 4; ++qq) {
        int gi = wave * (GPB / 4) + qq;
        int n  = ssize[gi];
        float4 outv = make_float4(0.f, 0.f, 0.f, 0.f);
        if (n > 0) {
            const fx4* p = (const fx4*)feats + (size_t)soff[gi] * 32;
            float sx = 0.f, sy = 0.f, sz = 0.f, sw = 0.f;
            float mx = NEG, my = NEG, mz = NEG, mw = NEG;
            int npairs = n >> 1;
            int i = 0;
            for (; i + 8 <= npairs; i += 8) {       // 8 float4 loads in flight
                fx4 v[8];
                #pragma unroll
                for (int u = 0; u < 8; ++u)
                    v[u] = __builtin_nontemporal_load(p + (size_t)(i + u) * 64 + lane);
                #pragma unroll
                for (int u = 0; u < 8; ++u) {
                    sx += v[u].x; sy += v[u].y; sz += v[u].z; sw += v[u].w;
                    mx = fmaxf(mx, v[u].x); my = fmaxf(my, v[u].y);
                    mz = fmaxf(mz, v[u].z); mw = fmaxf(mw, v[u].w);
                }
            }
            for (; i < npairs; ++i) {
                fx4 v = __builtin_nontemporal_load(p + (size_t)i * 64 + lane);
                sx += v.x; sy += v.y; sz += v.z; sw += v.w;
                mx = fmaxf(mx, v.x); my = fmaxf(my, v.y);
                mz = fmaxf(mz, v.z); mw = fmaxf(mw, v.w);
            }
            if ((n & 1) && lane < 32) {             // odd last row, lanes 0-31
                fx4 v = __builtin_nontemporal_load(p + (size_t)(n - 1) * 32 + lane);
                sx += v.x; sy += v.y; sz += v.z; sw += v.w;
                mx = fmaxf(mx, v.x); my = fmaxf(my, v.y);
                mz = fmaxf(mz, v.z); mw = fmaxf(mw, v.w);
            }
            // combine the two half-wave accumulators (opposite-parity rows)
            sx += __shfl_xor(sx, 32); sy += __shfl_xor(sy, 32);
            sz += __shfl_xor(sz, 32); sw += __shfl_xor(sw, 32);
            mx = fmaxf(mx, __shfl_xor(mx, 32)); my = fmaxf(my, __shfl_xor(my, 32));
            mz = fmaxf(mz, __shfl_xor(mz, 32)); mw = fmaxf(mw, __shfl_xor(mw, 32));
            if (lane < 32) {
                float invn = 1.0f / (float)n;
                outv = make_float4(sx * invn, sy * invn, sz * invn, sw * invn);
            } else {
                outv = make_float4(mx, my, mz, mw);
            }
        }
        X4[gi * 64 + lane] = outv;   // lanes 0-31: mean cols, 32-63: max cols
    }
    __syncthreads();

    // ---- layer 0: H0[GPB][256] = relu(X @ W0 + b0), W0 [256][256] row-major
    {
        float acc[GPB];
        float bb = b0[t];
        #pragma unroll
        for (int q = 0; q < GPB; ++q) acc[q] = bb;
        for (int k4 = 0; k4 < 64; ++k4) {
            const float* Wk = W0 + (size_t)k4 * 1024;
            float w0v = Wk[t], w1v = Wk[256 + t], w2v = Wk[512 + t], w3v = Wk[768 + t];
            #pragma unroll
            for (int q = 0; q < GPB; ++q) {
                float4 x = X4[q * 64 + k4];          // LDS broadcast
                acc[q] = fmaf(x.x, w0v, acc[q]);
                acc[q] = fmaf(x.y, w1v, acc[q]);
                acc[q] = fmaf(x.z, w2v, acc[q]);
                acc[q] = fmaf(x.w, w3v, acc[q]);
            }
        }
        #pragma unroll
        for (int q = 0; q < GPB; ++q)
            H0[q * 256 + t] = fmaxf(acc[q], 0.f);
    }
    __syncthreads();

    // ---- layer 1: H1[GPB][128] = relu(H0 @ W1 + b1), W1 [256][128]
    {
        int jl = t & 127;
        int gh = t >> 7;                              // wave-uniform
        float acc[4];
        float bb = b1[jl];
        #pragma unroll
        for (int q = 0; q < 4; ++q) acc[q] = bb;
        const float4* H04 = (const float4*)H0;
        for (int k4 = 0; k4 < 64; ++k4) {
            const float* Wk = W1 + (size_t)k4 * 512;
            float w0v = Wk[jl],       w1v = Wk[128 + jl];
            float w2v = Wk[256 + jl], w3v = Wk[384 + jl];
            #pragma unroll
            for (int q = 0; q < 4; ++q) {
                float4 x = H04[(gh * 4 + q) * 64 + k4];  // LDS broadcast
                acc[q] = fmaf(x.x, w0v, acc[q]);
                acc[q] = fmaf(x.y, w1v, acc[q]);
                acc[q] = fmaf(x.z, w2v, acc[q]);
                acc[q] = fmaf(x.w, w3v, acc[q]);
            }
        }
        #pragma unroll
        for (int q = 0; q < 4; ++q)
            H1[(gh * 4 + q) * 128 + jl] = fmaxf(acc[q], 0.f);
    }
    __syncthreads();

    // ---- layer 2: out[g] = sigmoid(H1[g] . W2 + b2)
    {
        int gi  = t >> 5;    // 0..7
        int sub = t & 31;
        float acc = 0.f;
        #pragma unroll
        for (int kk = 0; kk < 4; ++kk) {
            int k = sub + kk * 32;
            acc = fmaf(H1[gi * 128 + k], W2[k], acc);
        }
        acc += __shfl_xor(acc, 16);
        acc += __shfl_xor(acc, 8);
        acc += __shfl_xor(acc, 4);
        acc += __shfl_xor(acc, 2);
        acc += __shfl_xor(acc, 1);
        int g = g0 + gi;
        if (sub == 0 && g < G)
            out[g] = 1.0f / (1.0f + expf(-(acc + b2[0])));
    }
}

extern "C" void kernel_launch(void* const* d_in, const int* in_sizes, int n_in,
                              void* d_out, int out_size, void* d_ws, size_t ws_size,
                              hipStream_t stream) {
    const float* feats = (const float*)d_in[0];
    const int*   gsize = (const int*)d_in[1];
    const float* W0 = (const float*)d_in[2];
    const float* b0 = (const float*)d_in[3];
    const float* W1 = (const float*)d_in[4];
    const float* b1 = (const float*)d_in[5];
    const float* W2 = (const float*)d_in[6];
    const float* b2 = (const float*)d_in[7];
    float* out = (float*)d_out;

    int G = in_sizes[1];
    int blocks = (G + GPB - 1) / GPB;
    fused_pool_mlp_kernel<<<blocks, 256, 0, stream>>>(
        feats, gsize, W0, b0, W1, b1, W2, b2, out, G);
}